// Round 10
// baseline (302.779 us; speedup 1.0000x reference)
//
#include <hip/hip_runtime.h>

#define FDIM 128

typedef __attribute__((ext_vector_type(8))) short bf16x8;
typedef __attribute__((ext_vector_type(4))) float f32x4;

static __device__ __forceinline__ ushort f2bf(float f) {
    uint u = __float_as_uint(f);
    uint r = (u + 0x7FFF + ((u >> 16) & 1)) >> 16;
    return (ushort)r;
}
static __device__ __forceinline__ uint packbf(float lo, float hi) {
    return (uint)f2bf(lo) | ((uint)f2bf(hi) << 16);
}
static __device__ __forceinline__ float bflo(uint v) { return __uint_as_float(v << 16); }
static __device__ __forceinline__ float bfhi(uint v) { return __uint_as_float(v & 0xFFFF0000u); }

// ---------------- prep: convert x -> bf16 (normal + 16-col slabs), weights, histogram+scan ----------------

__global__ void prep_kernel(const float* __restrict__ x, ushort* __restrict__ xbn,
                            ushort* __restrict__ xbs, int nx8, int slabElems,
                            const float* __restrict__ W1l, const float* __restrict__ W1r,
                            const float* __restrict__ W2l, const float* __restrict__ W2r,
                            const float* __restrict__ W3, ushort* __restrict__ wbuf,
                            const int* __restrict__ dst, int E, int* __restrict__ bcnt,
                            int* __restrict__ hdone, int* __restrict__ bbase,
                            int* __restrict__ bcur, int nb, int nconv, int nhist) {
    const int b = blockIdx.x;
    const int tid = threadIdx.x;
    if (b < nconv) {
        int i = b * 256 + tid;
        if (i < nx8) {
            const float* s = x + (size_t)i * 8;
            float4 a = *(const float4*)(s);
            float4 c = *(const float4*)(s + 4);
            uint4 o;
            o.x = packbf(a.x, a.y); o.y = packbf(a.z, a.w);
            o.z = packbf(c.x, c.y); o.w = packbf(c.z, c.w);
            *(uint4*)(xbn + (size_t)i * 8) = o;
            int node = i >> 4, cch = i & 15;   // chunk of 8 cols; slab = cch>>1
            *(uint4*)(xbs + (size_t)(cch >> 1) * slabElems + (size_t)node * 16 + (cch & 1) * 8) = o;
        }
    } else if (b < nconv + 36) {
        int c = (b - nconv) * 256 + tid;      // 0..9215 chunks of 8
        const float* s; ushort* d;
        if (c < 2048)      { s = W1l + (size_t)c * 8;          d = wbuf + (size_t)c * 8; }
        else if (c < 4096) { s = W1r + (size_t)(c - 2048) * 8; d = wbuf + 16384 + (size_t)(c - 2048) * 8; }
        else if (c < 6144) { s = W2l + (size_t)(c - 4096) * 8; d = wbuf + 32768 + (size_t)(c - 4096) * 8; }
        else if (c < 8192) { s = W2r + (size_t)(c - 6144) * 8; d = wbuf + 49152 + (size_t)(c - 6144) * 8; }
        else               { s = W3  + (size_t)(c - 8192) * 8; d = wbuf + 65536 + (size_t)(c - 8192) * 8; }
        float4 a = *(const float4*)(s);
        float4 cc = *(const float4*)(s + 4);
        uint4 o;
        o.x = packbf(a.x, a.y); o.y = packbf(a.z, a.w);
        o.z = packbf(cc.x, cc.y); o.w = packbf(cc.z, cc.w);
        *(uint4*)d = o;
    } else {
        __shared__ int lh[256];
        __shared__ int isLast;
        int hb = b - nconv - 36;
        lh[tid] = 0;
        __syncthreads();
        #pragma unroll
        for (int k = 0; k < 8; ++k) {
            int e = hb * 2048 + k * 256 + tid;
            if (e < E) atomicAdd(&lh[dst[e] >> 8], 1);
        }
        __syncthreads();
        if (lh[tid]) atomicAdd(&bcnt[tid], lh[tid]);
        __syncthreads();
        if (tid == 0) {
            __threadfence();
            isLast = (atomicAdd(hdone, 1) == nhist - 1);
        }
        __syncthreads();
        if (isLast && tid < 64) {
            __threadfence();
            volatile int* vb = bcnt;
            const int i0 = tid * 4;
            int v0 = (i0 + 0 < nb) ? vb[i0 + 0] : 0;
            int v1 = (i0 + 1 < nb) ? vb[i0 + 1] : 0;
            int v2 = (i0 + 2 < nb) ? vb[i0 + 2] : 0;
            int v3 = (i0 + 3 < nb) ? vb[i0 + 3] : 0;
            int s = v0 + v1 + v2 + v3;
            int incl = s;
            #pragma unroll
            for (int d = 1; d < 64; d <<= 1) {
                int t = __shfl_up(incl, d);
                if (tid >= d) incl += t;
            }
            int excl = incl - s;
            int e0 = excl, e1 = excl + v0, e2 = e1 + v1, e3 = e2 + v2;
            if (i0 + 0 < nb) { bbase[i0 + 0] = e0; bcur[i0 + 0] = e0; }
            if (i0 + 1 < nb) { bbase[i0 + 1] = e1; bcur[i0 + 1] = e1; }
            if (i0 + 2 < nb) { bbase[i0 + 2] = e2; bcur[i0 + 2] = e2; }
            if (i0 + 3 < nb) { bbase[i0 + 3] = e3; bcur[i0 + 3] = e3; }
            int total = __shfl(incl, 63);
            if (tid == 0) bbase[nb] = total;
        }
    }
}

// ---------------- bin edges into bucket-contiguous packed (src | dlow<<24) ----------------

__global__ void pair_scatter(const int* __restrict__ src, const int* __restrict__ dst,
                             int* __restrict__ bcur, uint* __restrict__ pairs, int E) {
    __shared__ int lh[256];
    __shared__ int gb[256];
    const int tid = threadIdx.x;
    lh[tid] = 0;
    __syncthreads();
    int ss[8], dd[8], sl[8];
    #pragma unroll
    for (int k = 0; k < 8; ++k) {
        int e = blockIdx.x * 2048 + k * 256 + tid;
        if (e < E) {
            ss[k] = src[e];
            dd[k] = dst[e];
            sl[k] = atomicAdd(&lh[dd[k] >> 8], 1);
        } else dd[k] = -1;
    }
    __syncthreads();
    if (lh[tid]) gb[tid] = atomicAdd(&bcur[tid], lh[tid]);
    __syncthreads();
    #pragma unroll
    for (int k = 0; k < 8; ++k) {
        if (dd[k] >= 0)
            pairs[gb[dd[k] >> 8] + sl[k]] = (uint)ss[k] | ((uint)(dd[k] & 255) << 24);
    }
}

// ---------------- per-bucket CSR: LDS count/scan/scatter ----------------

__global__ void bucket_csr(const uint* __restrict__ pairs, const int* __restrict__ bbase,
                           int* __restrict__ off, int* __restrict__ csr, int N) {
    __shared__ int cnt[256];
    __shared__ int base[256];
    __shared__ int cur[256];
    const int b = blockIdx.x;
    const int tid = threadIdx.x;
    const int p0 = bbase[b], p1 = bbase[b + 1];
    cnt[tid] = 0;
    __syncthreads();
    for (int p = p0 + tid; p < p1; p += 256) atomicAdd(&cnt[pairs[p] >> 24], 1);
    __syncthreads();
    if (tid < 64) {
        int i0 = tid * 4;
        int v0 = cnt[i0], v1 = cnt[i0 + 1], v2 = cnt[i0 + 2], v3 = cnt[i0 + 3];
        int s = v0 + v1 + v2 + v3;
        int incl = s;
        #pragma unroll
        for (int d = 1; d < 64; d <<= 1) {
            int t = __shfl_up(incl, d);
            if (tid >= d) incl += t;
        }
        int excl = incl - s;
        base[i0] = excl; base[i0 + 1] = excl + v0;
        base[i0 + 2] = excl + v0 + v1; base[i0 + 3] = excl + v0 + v1 + v2;
        cur[i0] = base[i0]; cur[i0 + 1] = base[i0 + 1];
        cur[i0 + 2] = base[i0 + 2]; cur[i0 + 3] = base[i0 + 3];
    }
    __syncthreads();
    int node = (b << 8) + tid;
    if (node <= N) off[node] = p0 + base[tid];
    for (int p = p0 + tid; p < p1; p += 256) {
        uint e = pairs[p];
        int slot = atomicAdd(&cur[e >> 24], 1);
        csr[p0 + slot] = (int)(e & 0xFFFFFF);
    }
}

// ---------------- XCD-pinned sliced gather-mean ----------------
// slab = blockIdx & 7 -> with round-robin workgroup dispatch, all blocks reading
// slab k run on XCD k, so the 1.6 MB slab stays L2-resident and the full 16x
// per-row reuse is captured inside one L2. Wave = 1 node at a time: 16 neighbor
// slots x 4 lanes x uint2 (8 B) = 512 B / load inst, 2-deep unrolled.

__global__ __launch_bounds__(256, 8)
void agg_xcd(const ushort* __restrict__ slabs, const int* __restrict__ off,
             const int* __restrict__ csr, ushort* __restrict__ agg,
             int slabElems, int n) {
    const int slab = blockIdx.x & 7;
    const int nb   = blockIdx.x >> 3;
    const ushort* __restrict__ slabp = slabs + (size_t)slab * slabElems;
    const int lane = threadIdx.x & 63;
    const int wid  = threadIdx.x >> 6;
    const int g = lane >> 2;      // neighbor slot 0..15
    const int q = lane & 3;       // 8B chunk 0..3 within 32B slab row

    for (int i = 0; i < 8; ++i) {
        const int node = nb * 32 + wid * 8 + i;
        if (node >= n) return;
        const int j0 = off[node], j1 = off[node + 1];
        float a0 = 0.f, a1 = 0.f, a2 = 0.f, a3 = 0.f;
        int j = j0 + g;
        for (; j + 16 < j1; j += 32) {
            int s0 = csr[j], s1 = csr[j + 16];
            uint2 v0 = *(const uint2*)(slabp + (size_t)s0 * 16 + q * 4);
            uint2 v1 = *(const uint2*)(slabp + (size_t)s1 * 16 + q * 4);
            a0 += bflo(v0.x) + bflo(v1.x); a1 += bfhi(v0.x) + bfhi(v1.x);
            a2 += bflo(v0.y) + bflo(v1.y); a3 += bfhi(v0.y) + bfhi(v1.y);
        }
        if (j < j1) {
            uint2 v0 = *(const uint2*)(slabp + (size_t)csr[j] * 16 + q * 4);
            a0 += bflo(v0.x); a1 += bfhi(v0.x);
            a2 += bflo(v0.y); a3 += bfhi(v0.y);
        }
        a0 += __shfl_xor(a0, 4);  a1 += __shfl_xor(a1, 4);
        a2 += __shfl_xor(a2, 4);  a3 += __shfl_xor(a3, 4);
        a0 += __shfl_xor(a0, 8);  a1 += __shfl_xor(a1, 8);
        a2 += __shfl_xor(a2, 8);  a3 += __shfl_xor(a3, 8);
        a0 += __shfl_xor(a0, 16); a1 += __shfl_xor(a1, 16);
        a2 += __shfl_xor(a2, 16); a3 += __shfl_xor(a3, 16);
        a0 += __shfl_xor(a0, 32); a1 += __shfl_xor(a1, 32);
        a2 += __shfl_xor(a2, 32); a3 += __shfl_xor(a3, 32);
        if (g == 0) {
            float inv = 1.0f / fmaxf((float)(j1 - j0), 1.0f);
            uint2 o;
            o.x = packbf(a0 * inv, a1 * inv);
            o.y = packbf(a2 * inv, a3 * inv);
            *(uint2*)(agg + (size_t)node * FDIM + slab * 16 + q * 4) = o;
        }
    }
}

// ---------------- MFMA SAGE linear 1: h1 = relu(agg@Wl^T + x@Wr^T + b), dual-layout out ----------------

__global__ void sage_linear_mfma(const ushort* __restrict__ agg, const ushort* __restrict__ xin,
                                 const ushort* __restrict__ Wl, const ushort* __restrict__ Wr,
                                 const float* __restrict__ bias, ushort* __restrict__ outn,
                                 ushort* __restrict__ outs, int slabElems, int n) {
    __shared__ __align__(16) ushort As[32 * FDIM];
    __shared__ __align__(16) ushort Xs[32 * FDIM];
    const int row0 = blockIdx.x * 32;
    const int lane = threadIdx.x & 63;
    const int wid  = threadIdx.x >> 6;
    const int wrow = wid & 1;
    const int wcol = wid >> 1;

    const float4 z4 = make_float4(0.f, 0.f, 0.f, 0.f);
    #pragma unroll
    for (int i = 0; i < 2; ++i) {
        int s = threadIdx.x + i * 256;
        int r = s >> 4, cch = s & 15;
        int row = row0 + r;
        float4 va = z4, vx = z4;
        if (row < n) {
            va = *(const float4*)(agg + (size_t)row * FDIM + cch * 8);
            vx = *(const float4*)(xin + (size_t)row * FDIM + cch * 8);
        }
        int sc = cch ^ (r & 7);
        *(float4*)(As + (r * 16 + sc) * 8) = va;
        *(float4*)(Xs + (r * 16 + sc) * 8) = vx;
    }
    __syncthreads();

    const int lr = lane & 15;
    const int lk = lane >> 4;

    f32x4 acc[4];
    #pragma unroll
    for (int t = 0; t < 4; ++t) acc[t] = (f32x4){0.f, 0.f, 0.f, 0.f};

    const int arow = wrow * 16 + lr;
    #pragma unroll
    for (int ks = 0; ks < 4; ++ks) {
        bf16x8 a = *(const bf16x8*)(As + (arow * 16 + ((ks * 4 + lk) ^ (arow & 7))) * 8);
        #pragma unroll
        for (int t = 0; t < 4; ++t) {
            int wr = wcol * 64 + t * 16 + lr;
            bf16x8 bb = *(const bf16x8*)(Wl + (size_t)wr * FDIM + ks * 32 + lk * 8);
            acc[t] = __builtin_amdgcn_mfma_f32_16x16x32_bf16(a, bb, acc[t], 0, 0, 0);
        }
    }
    #pragma unroll
    for (int ks = 0; ks < 4; ++ks) {
        bf16x8 a = *(const bf16x8*)(Xs + (arow * 16 + ((ks * 4 + lk) ^ (arow & 7))) * 8);
        #pragma unroll
        for (int t = 0; t < 4; ++t) {
            int wr = wcol * 64 + t * 16 + lr;
            bf16x8 bb = *(const bf16x8*)(Wr + (size_t)wr * FDIM + ks * 32 + lk * 8);
            acc[t] = __builtin_amdgcn_mfma_f32_16x16x32_bf16(a, bb, acc[t], 0, 0, 0);
        }
    }

    #pragma unroll
    for (int t = 0; t < 4; ++t) {
        int col = wcol * 64 + t * 16 + lr;
        float bc = bias[col];
        ushort* slb = outs + (size_t)(col >> 4) * slabElems + (col & 15);
        #pragma unroll
        for (int j = 0; j < 4; ++j) {
            int row = row0 + wrow * 16 + lk * 4 + j;
            if (row < n) {
                ushort hv = f2bf(fmaxf(acc[t][j] + bc, 0.f));
                outn[(size_t)row * FDIM + col] = hv;
                slb[(size_t)row * 16] = hv;
            }
        }
    }
}

// ---------------- fused layer-2 linear + head ----------------

__global__ void sage_linear2_head(const ushort* __restrict__ agg, const ushort* __restrict__ xin,
                                  const ushort* __restrict__ Wl, const ushort* __restrict__ Wr,
                                  const float* __restrict__ bias,
                                  const ushort* __restrict__ W3, const float* __restrict__ b3,
                                  float* __restrict__ out, int n) {
    __shared__ __align__(16) ushort As[32 * FDIM];
    __shared__ __align__(16) ushort Xs[32 * FDIM];
    const int row0 = blockIdx.x * 32;
    const int lane = threadIdx.x & 63;
    const int wid  = threadIdx.x >> 6;
    const int wrow = wid & 1;
    const int wcol = wid >> 1;

    const float4 z4 = make_float4(0.f, 0.f, 0.f, 0.f);
    #pragma unroll
    for (int i = 0; i < 2; ++i) {
        int s = threadIdx.x + i * 256;
        int r = s >> 4, cch = s & 15;
        int row = row0 + r;
        float4 va = z4, vx = z4;
        if (row < n) {
            va = *(const float4*)(agg + (size_t)row * FDIM + cch * 8);
            vx = *(const float4*)(xin + (size_t)row * FDIM + cch * 8);
        }
        int sc = cch ^ (r & 7);
        *(float4*)(As + (r * 16 + sc) * 8) = va;
        *(float4*)(Xs + (r * 16 + sc) * 8) = vx;
    }
    __syncthreads();

    const int lr = lane & 15;
    const int lk = lane >> 4;

    f32x4 acc[4];
    #pragma unroll
    for (int t = 0; t < 4; ++t) acc[t] = (f32x4){0.f, 0.f, 0.f, 0.f};

    const int arow = wrow * 16 + lr;
    #pragma unroll
    for (int ks = 0; ks < 4; ++ks) {
        bf16x8 a = *(const bf16x8*)(As + (arow * 16 + ((ks * 4 + lk) ^ (arow & 7))) * 8);
        #pragma unroll
        for (int t = 0; t < 4; ++t) {
            int wr = wcol * 64 + t * 16 + lr;
            bf16x8 bb = *(const bf16x8*)(Wl + (size_t)wr * FDIM + ks * 32 + lk * 8);
            acc[t] = __builtin_amdgcn_mfma_f32_16x16x32_bf16(a, bb, acc[t], 0, 0, 0);
        }
    }
    #pragma unroll
    for (int ks = 0; ks < 4; ++ks) {
        bf16x8 a = *(const bf16x8*)(Xs + (arow * 16 + ((ks * 4 + lk) ^ (arow & 7))) * 8);
        #pragma unroll
        for (int t = 0; t < 4; ++t) {
            int wr = wcol * 64 + t * 16 + lr;
            bf16x8 bb = *(const bf16x8*)(Wr + (size_t)wr * FDIM + ks * 32 + lk * 8);
            acc[t] = __builtin_amdgcn_mfma_f32_16x16x32_bf16(a, bb, acc[t], 0, 0, 0);
        }
    }

    __syncthreads();
    #pragma unroll
    for (int t = 0; t < 4; ++t) {
        int col = wcol * 64 + t * 16 + lr;
        float bc = bias[col];
        #pragma unroll
        for (int j = 0; j < 4; ++j) {
            int r = wrow * 16 + lk * 4 + j;
            float v = fmaxf(acc[t][j] + bc, 0.f);
            As[(r * 16 + ((col >> 3) ^ (r & 7))) * 8 + (col & 7)] = f2bf(v);
        }
    }
    __syncthreads();

    f32x4 acc2[2];
    #pragma unroll
    for (int t = 0; t < 2; ++t) acc2[t] = (f32x4){0.f, 0.f, 0.f, 0.f};

    #pragma unroll
    for (int ks = 0; ks < 4; ++ks) {
        bf16x8 a = *(const bf16x8*)(As + (arow * 16 + ((ks * 4 + lk) ^ (arow & 7))) * 8);
        #pragma unroll
        for (int t = 0; t < 2; ++t) {
            int wr = wcol * 32 + t * 16 + lr;
            bf16x8 bb = *(const bf16x8*)(W3 + (size_t)wr * FDIM + ks * 32 + lk * 8);
            acc2[t] = __builtin_amdgcn_mfma_f32_16x16x32_bf16(a, bb, acc2[t], 0, 0, 0);
        }
    }

    #pragma unroll
    for (int t = 0; t < 2; ++t) {
        int col = wcol * 32 + t * 16 + lr;
        float bc = b3[col];
        #pragma unroll
        for (int j = 0; j < 4; ++j) {
            int row = row0 + wrow * 16 + lk * 4 + j;
            if (row < n) out[(size_t)row * 64 + col] = acc2[t][j] + bc;
        }
    }
}

// ---------------- launch ----------------

extern "C" void kernel_launch(void* const* d_in, const int* in_sizes, int n_in,
                              void* d_out, int out_size, void* d_ws, size_t ws_size,
                              hipStream_t stream) {
    const float* x   = (const float*)d_in[0];
    const int*   ei  = (const int*)d_in[1];
    const float* W1l = (const float*)d_in[2];
    const float* b1  = (const float*)d_in[3];
    const float* W1r = (const float*)d_in[4];
    const float* W2l = (const float*)d_in[5];
    const float* b2  = (const float*)d_in[6];
    const float* W2r = (const float*)d_in[7];
    const float* W3  = (const float*)d_in[8];
    const float* b3  = (const float*)d_in[9];
    float* out = (float*)d_out;

    const int N = in_sizes[0] / FDIM;   // 50000
    const int E = in_sizes[1] / 2;      // 800000
    const int* src = ei;
    const int* dst = ei + E;
    const int NBK = (N + 255) >> 8;     // 196
    const int slabElems = N * 16;       // ushorts per 16-col slab (1.6 MB)

    char* ws = (char*)d_ws;
    size_t p = 0;
    auto alloc = [&](size_t bytes) {
        char* q = ws + p;
        p += (bytes + 255) & ~(size_t)255;
        return q;
    };
    int* ctrl    = (int*)alloc(272 * 4);          // bcnt[256] + hdone
    int* bcnt    = ctrl;
    int* hdone   = ctrl + 256;
    int* bbase   = (int*)alloc(260 * 4);
    int* bcur    = (int*)alloc(256 * 4);
    uint* pairs  = (uint*)alloc((size_t)E * 4);
    int* csr     = (int*)alloc((size_t)E * 4);
    int* off     = (int*)alloc((size_t)(N + 1) * 4);
    ushort* xbn  = (ushort*)alloc((size_t)N * FDIM * 2);
    ushort* xbs  = (ushort*)alloc((size_t)N * FDIM * 2);   // 8 slabs of 16 cols
    ushort* h1n  = (ushort*)alloc((size_t)N * FDIM * 2);
    ushort* h1s  = (ushort*)alloc((size_t)N * FDIM * 2);   // 8 slabs
    ushort* agb  = (ushort*)alloc((size_t)N * FDIM * 2);
    ushort* wbuf = (ushort*)alloc(73728 * 2);
    ushort* w1l = wbuf, *w1r = wbuf + 16384, *w2l = wbuf + 32768,
           *w2r = wbuf + 49152, *w3 = wbuf + 65536;

    hipMemsetAsync(ctrl, 0, 257 * 4, stream);

    const int nx8   = N * FDIM / 8;         // 800000
    const int nconv = (nx8 + 255) / 256;    // 3125
    const int nhist = (E + 2047) / 2048;    // 391
    prep_kernel<<<nconv + 36 + nhist, 256, 0, stream>>>(
        x, xbn, xbs, nx8, slabElems, W1l, W1r, W2l, W2r, W3, wbuf, dst, E, bcnt,
        hdone, bbase, bcur, NBK, nconv, nhist);
    pair_scatter<<<(E + 2047) / 2048, 256, 0, stream>>>(src, dst, bcur, pairs, E);
    bucket_csr<<<NBK, 256, 0, stream>>>(pairs, bbase, off, csr, N);

    const int agrid = ((N + 31) / 32) * 8;   // 1563 node-blocks x 8 slabs
    const int lgrid = (N + 31) / 32;         // 1563

    agg_xcd<<<agrid, 256, 0, stream>>>(xbs, off, csr, agb, slabElems, N);
    sage_linear_mfma<<<lgrid, 256, 0, stream>>>(agb, xbn, w1l, w1r, b1, h1n, h1s, slabElems, N);
    agg_xcd<<<agrid, 256, 0, stream>>>(h1s, off, csr, agb, slabElems, N);
    sage_linear2_head<<<lgrid, 256, 0, stream>>>(agb, h1n, w2l, w2r, b2, w3, b3, out, N);
}

// Round 11
// 166.048 us; speedup vs baseline: 1.8234x; 1.8234x over previous
//
#include <hip/hip_runtime.h>

#define FDIM 128

typedef __attribute__((ext_vector_type(8))) short bf16x8;
typedef __attribute__((ext_vector_type(4))) float f32x4;
typedef __attribute__((ext_vector_type(2))) float f32x2;

static __device__ __forceinline__ ushort f2bf(float f) {
    uint u = __float_as_uint(f);
    uint r = (u + 0x7FFF + ((u >> 16) & 1)) >> 16;
    return (ushort)r;
}
static __device__ __forceinline__ uint packbf(float lo, float hi) {
    return (uint)f2bf(lo) | ((uint)f2bf(hi) << 16);
}
static __device__ __forceinline__ uint pk8(float a, float b, float c, float d) {
    uint u = __builtin_amdgcn_cvt_pk_fp8_f32(a, b, 0, false);
    return __builtin_amdgcn_cvt_pk_fp8_f32(c, d, u, true);
}
static __device__ __forceinline__ uchar pk1(float v) {
    return (uchar)(__builtin_amdgcn_cvt_pk_fp8_f32(v, v, 0, false) & 0xFF);
}

// unpack 8 fp8 (uint2) and accumulate into a[0..7]
#define ACCF8(A, V) do { \
    f32x2 p0 = __builtin_amdgcn_cvt_pk_f32_fp8((V).x, false); \
    f32x2 p1 = __builtin_amdgcn_cvt_pk_f32_fp8((V).x, true);  \
    f32x2 p2 = __builtin_amdgcn_cvt_pk_f32_fp8((V).y, false); \
    f32x2 p3 = __builtin_amdgcn_cvt_pk_f32_fp8((V).y, true);  \
    A[0] += p0.x; A[1] += p0.y; A[2] += p1.x; A[3] += p1.y;   \
    A[4] += p2.x; A[5] += p2.y; A[6] += p3.x; A[7] += p3.y; } while (0)

// ---------------- prep: x -> bf16 + fp8 tables, weights bf16, histogram+scan ----------------

__global__ void prep_kernel(const float* __restrict__ x, ushort* __restrict__ xbn,
                            uchar* __restrict__ xf8, int nx8,
                            const float* __restrict__ W1l, const float* __restrict__ W1r,
                            const float* __restrict__ W2l, const float* __restrict__ W2r,
                            const float* __restrict__ W3, ushort* __restrict__ wbuf,
                            const int* __restrict__ dst, int E, int* __restrict__ bcnt,
                            int* __restrict__ hdone, int* __restrict__ bbase,
                            int* __restrict__ bcur, int nb, int nconv, int nhist) {
    const int b = blockIdx.x;
    const int tid = threadIdx.x;
    if (b < nconv) {
        int i = b * 256 + tid;
        if (i < nx8) {
            const float* s = x + (size_t)i * 8;
            float4 a = *(const float4*)(s);
            float4 c = *(const float4*)(s + 4);
            uint4 o;
            o.x = packbf(a.x, a.y); o.y = packbf(a.z, a.w);
            o.z = packbf(c.x, c.y); o.w = packbf(c.z, c.w);
            *(uint4*)(xbn + (size_t)i * 8) = o;
            uint2 q;
            q.x = pk8(a.x, a.y, a.z, a.w);
            q.y = pk8(c.x, c.y, c.z, c.w);
            *(uint2*)(xf8 + (size_t)i * 8) = q;
        }
    } else if (b < nconv + 36) {
        int c = (b - nconv) * 256 + tid;      // 0..9215 chunks of 8
        const float* s; ushort* d;
        if (c < 2048)      { s = W1l + (size_t)c * 8;          d = wbuf + (size_t)c * 8; }
        else if (c < 4096) { s = W1r + (size_t)(c - 2048) * 8; d = wbuf + 16384 + (size_t)(c - 2048) * 8; }
        else if (c < 6144) { s = W2l + (size_t)(c - 4096) * 8; d = wbuf + 32768 + (size_t)(c - 4096) * 8; }
        else if (c < 8192) { s = W2r + (size_t)(c - 6144) * 8; d = wbuf + 49152 + (size_t)(c - 6144) * 8; }
        else               { s = W3  + (size_t)(c - 8192) * 8; d = wbuf + 65536 + (size_t)(c - 8192) * 8; }
        float4 a = *(const float4*)(s);
        float4 cc = *(const float4*)(s + 4);
        uint4 o;
        o.x = packbf(a.x, a.y); o.y = packbf(a.z, a.w);
        o.z = packbf(cc.x, cc.y); o.w = packbf(cc.z, cc.w);
        *(uint4*)d = o;
    } else {
        __shared__ int lh[256];
        __shared__ int isLast;
        int hb = b - nconv - 36;
        lh[tid] = 0;
        __syncthreads();
        #pragma unroll
        for (int k = 0; k < 8; ++k) {
            int e = hb * 2048 + k * 256 + tid;
            if (e < E) atomicAdd(&lh[dst[e] >> 8], 1);
        }
        __syncthreads();
        if (lh[tid]) atomicAdd(&bcnt[tid], lh[tid]);
        __syncthreads();
        if (tid == 0) {
            __threadfence();
            isLast = (atomicAdd(hdone, 1) == nhist - 1);
        }
        __syncthreads();
        if (isLast && tid < 64) {
            __threadfence();
            volatile int* vb = bcnt;
            const int i0 = tid * 4;
            int v0 = (i0 + 0 < nb) ? vb[i0 + 0] : 0;
            int v1 = (i0 + 1 < nb) ? vb[i0 + 1] : 0;
            int v2 = (i0 + 2 < nb) ? vb[i0 + 2] : 0;
            int v3 = (i0 + 3 < nb) ? vb[i0 + 3] : 0;
            int s = v0 + v1 + v2 + v3;
            int incl = s;
            #pragma unroll
            for (int d = 1; d < 64; d <<= 1) {
                int t = __shfl_up(incl, d);
                if (tid >= d) incl += t;
            }
            int excl = incl - s;
            int e0 = excl, e1 = excl + v0, e2 = e1 + v1, e3 = e2 + v2;
            if (i0 + 0 < nb) { bbase[i0 + 0] = e0; bcur[i0 + 0] = e0; }
            if (i0 + 1 < nb) { bbase[i0 + 1] = e1; bcur[i0 + 1] = e1; }
            if (i0 + 2 < nb) { bbase[i0 + 2] = e2; bcur[i0 + 2] = e2; }
            if (i0 + 3 < nb) { bbase[i0 + 3] = e3; bcur[i0 + 3] = e3; }
            int total = __shfl(incl, 63);
            if (tid == 0) bbase[nb] = total;
        }
    }
}

// ---------------- bin edges into bucket-contiguous packed (src | dlow<<24) ----------------

__global__ void pair_scatter(const int* __restrict__ src, const int* __restrict__ dst,
                             int* __restrict__ bcur, uint* __restrict__ pairs, int E) {
    __shared__ int lh[256];
    __shared__ int gb[256];
    const int tid = threadIdx.x;
    lh[tid] = 0;
    __syncthreads();
    int ss[8], dd[8], sl[8];
    #pragma unroll
    for (int k = 0; k < 8; ++k) {
        int e = blockIdx.x * 2048 + k * 256 + tid;
        if (e < E) {
            ss[k] = src[e];
            dd[k] = dst[e];
            sl[k] = atomicAdd(&lh[dd[k] >> 8], 1);
        } else dd[k] = -1;
    }
    __syncthreads();
    if (lh[tid]) gb[tid] = atomicAdd(&bcur[tid], lh[tid]);
    __syncthreads();
    #pragma unroll
    for (int k = 0; k < 8; ++k) {
        if (dd[k] >= 0)
            pairs[gb[dd[k] >> 8] + sl[k]] = (uint)ss[k] | ((uint)(dd[k] & 255) << 24);
    }
}

// ---------------- per-bucket CSR: LDS count/scan/scatter ----------------

__global__ void bucket_csr(const uint* __restrict__ pairs, const int* __restrict__ bbase,
                           int* __restrict__ off, int* __restrict__ csr, int N) {
    __shared__ int cnt[256];
    __shared__ int base[256];
    __shared__ int cur[256];
    const int b = blockIdx.x;
    const int tid = threadIdx.x;
    const int p0 = bbase[b], p1 = bbase[b + 1];
    cnt[tid] = 0;
    __syncthreads();
    for (int p = p0 + tid; p < p1; p += 256) atomicAdd(&cnt[pairs[p] >> 24], 1);
    __syncthreads();
    if (tid < 64) {
        int i0 = tid * 4;
        int v0 = cnt[i0], v1 = cnt[i0 + 1], v2 = cnt[i0 + 2], v3 = cnt[i0 + 3];
        int s = v0 + v1 + v2 + v3;
        int incl = s;
        #pragma unroll
        for (int d = 1; d < 64; d <<= 1) {
            int t = __shfl_up(incl, d);
            if (tid >= d) incl += t;
        }
        int excl = incl - s;
        base[i0] = excl; base[i0 + 1] = excl + v0;
        base[i0 + 2] = excl + v0 + v1; base[i0 + 3] = excl + v0 + v1 + v2;
        cur[i0] = base[i0]; cur[i0 + 1] = base[i0 + 1];
        cur[i0 + 2] = base[i0 + 2]; cur[i0 + 3] = base[i0 + 3];
    }
    __syncthreads();
    int node = (b << 8) + tid;
    if (node <= N) off[node] = p0 + base[tid];
    for (int p = p0 + tid; p < p1; p += 256) {
        uint e = pairs[p];
        int slot = atomicAdd(&cur[e >> 24], 1);
        csr[p0 + slot] = (int)(e & 0xFFFFFF);
    }
}

// ---------------- fused SAGE layer, 16-row tiles, fp8 gather ----------------
// block = 256 thr (4 waves), 16 nodes/block, grid = 3125.
// Gather: wave w gathers nodes w*4..w*4+3; quarter-wave slots; fp8 rows (128 B):
// 16 lanes x uint2 (8 B), 4-deep unrolled; fp32 accum via v_cvt_pk_f32_fp8.
// Self rows (Xs) stay bf16. MFMA: operand-split waves, psum merge.
// HEAD=0: write h bf16 + fp8 table. HEAD=1: keep h in LDS, W3 head -> fp32 out.

#define PS 132

template<int HEAD>
__global__ __launch_bounds__(256, 8)
void fused_sage(const uchar* __restrict__ feat8, const ushort* __restrict__ featn,
                const int* __restrict__ off, const int* __restrict__ csr,
                const ushort* __restrict__ Wl, const ushort* __restrict__ Wr,
                const float* __restrict__ bias,
                const ushort* __restrict__ W3, const float* __restrict__ b3,
                ushort* __restrict__ houtn, uchar* __restrict__ hout8,
                float* __restrict__ fout, int n) {
    __shared__ __align__(16) ushort As[16 * FDIM];
    __shared__ __align__(16) ushort Xs[16 * FDIM];
    __shared__ __align__(16) float psum[16 * PS];
    const int row0 = blockIdx.x * 16;
    const int lane = threadIdx.x & 63;
    const int wid  = threadIdx.x >> 6;

    // stage self rows (bf16): 16 rows x 16 chunks = 256 threads, one 16B load each
    {
        int r = threadIdx.x >> 4, cch = threadIdx.x & 15;
        int row = row0 + r;
        float4 vx = make_float4(0.f, 0.f, 0.f, 0.f);
        if (row < n) vx = *(const float4*)(featn + (size_t)row * FDIM + cch * 8);
        *(float4*)(Xs + (r * 16 + (cch ^ (r & 7))) * 8) = vx;
    }

    // gather-mean from fp8 table: 4 nodes per wave, quarter-wave neighbor slots
    const int g = lane >> 4;      // neighbor slot 0..3
    const int c = lane & 15;      // 8B chunk 0..15 within 128B row
    #define LDROW(s) (*(const uint2*)(feat8 + (size_t)(s) * FDIM + c * 8))
    for (int i = 0; i < 4; ++i) {
        const int r = wid * 4 + i;
        const int node = row0 + r;
        float a[8] = {0.f, 0.f, 0.f, 0.f, 0.f, 0.f, 0.f, 0.f};
        float inv = 0.f;
        if (node < n) {
            const int j0 = off[node], j1 = off[node + 1];
            int j = j0 + g;
            for (; j + 12 < j1; j += 16) {
                int s0 = csr[j], s1 = csr[j + 4], s2 = csr[j + 8], s3 = csr[j + 12];
                uint2 v0 = LDROW(s0), v1 = LDROW(s1), v2 = LDROW(s2), v3 = LDROW(s3);
                ACCF8(a, v0); ACCF8(a, v1); ACCF8(a, v2); ACCF8(a, v3);
            }
            for (; j + 4 < j1; j += 8) {
                int s0 = csr[j], s1 = csr[j + 4];
                uint2 v0 = LDROW(s0), v1 = LDROW(s1);
                ACCF8(a, v0); ACCF8(a, v1);
            }
            for (; j < j1; j += 4) {
                uint2 v0 = LDROW(csr[j]);
                ACCF8(a, v0);
            }
            inv = 1.0f / fmaxf((float)(j1 - j0), 1.0f);
        }
        #pragma unroll
        for (int k = 0; k < 8; ++k) {
            a[k] += __shfl_xor(a[k], 16);
            a[k] += __shfl_xor(a[k], 32);
        }
        if (g == 0) {
            // lane c holds cols c*8..c*8+7 of the mean row -> bf16 into As (swizzled)
            uint4 o;
            o.x = packbf(a[0] * inv, a[1] * inv);
            o.y = packbf(a[2] * inv, a[3] * inv);
            o.z = packbf(a[4] * inv, a[5] * inv);
            o.w = packbf(a[6] * inv, a[7] * inv);
            *(uint4*)(As + (r * 16 + (c ^ (r & 7))) * 8) = o;
        }
    }
    #undef LDROW
    __syncthreads();

    // MFMA: wave role (op, half)
    const int op   = wid >> 1;          // 0: As@Wl, 1: Xs@Wr
    const int half = wid & 1;           // column half (64 cols)
    const int lr = lane & 15;
    const int lk = lane >> 4;
    const ushort* Atile = op ? Xs : As;
    const ushort* W     = op ? Wr : Wl;

    f32x4 acc[4];
    #pragma unroll
    for (int t = 0; t < 4; ++t) acc[t] = (f32x4){0.f, 0.f, 0.f, 0.f};

    #pragma unroll
    for (int ks = 0; ks < 4; ++ks) {
        bf16x8 a = *(const bf16x8*)(Atile + (lr * 16 + ((ks * 4 + lk) ^ (lr & 7))) * 8);
        #pragma unroll
        for (int t = 0; t < 4; ++t) {
            int wr = half * 64 + t * 16 + lr;
            bf16x8 bb = *(const bf16x8*)(W + (size_t)wr * FDIM + ks * 32 + lk * 8);
            acc[t] = __builtin_amdgcn_mfma_f32_16x16x32_bf16(a, bb, acc[t], 0, 0, 0);
        }
    }

    if (op == 1) {
        #pragma unroll
        for (int t = 0; t < 4; ++t) {
            #pragma unroll
            for (int j = 0; j < 4; ++j)
                psum[(lk * 4 + j) * PS + half * 64 + t * 16 + lr] = acc[t][j];
        }
    }
    __syncthreads();

    if (op == 0) {
        #pragma unroll
        for (int t = 0; t < 4; ++t) {
            int col = half * 64 + t * 16 + lr;
            float bc = bias[col];
            #pragma unroll
            for (int j = 0; j < 4; ++j) {
                int r = lk * 4 + j;
                float v = fmaxf(acc[t][j] + psum[r * PS + col] + bc, 0.f);
                if (HEAD == 0) {
                    int row = row0 + r;
                    if (row < n) {
                        houtn[(size_t)row * FDIM + col] = f2bf(v);
                        hout8[(size_t)row * FDIM + col] = pk1(v);
                    }
                } else {
                    As[(r * 16 + ((col >> 3) ^ (r & 7))) * 8 + (col & 7)] = f2bf(v);
                }
            }
        }
    }

    if (HEAD == 1) {
        __syncthreads();
        // head: out = h2 @ W3^T + b3; each wave: 16 out cols (wid*16)
        f32x4 acc2 = (f32x4){0.f, 0.f, 0.f, 0.f};
        #pragma unroll
        for (int ks = 0; ks < 4; ++ks) {
            bf16x8 a = *(const bf16x8*)(As + (lr * 16 + ((ks * 4 + lk) ^ (lr & 7))) * 8);
            int wr = wid * 16 + lr;
            bf16x8 bb = *(const bf16x8*)(W3 + (size_t)wr * FDIM + ks * 32 + lk * 8);
            acc2 = __builtin_amdgcn_mfma_f32_16x16x32_bf16(a, bb, acc2, 0, 0, 0);
        }
        int col = wid * 16 + lr;
        float bc = b3[col];
        #pragma unroll
        for (int j = 0; j < 4; ++j) {
            int row = row0 + lk * 4 + j;
            if (row < n) fout[(size_t)row * 64 + col] = acc2[j] + bc;
        }
    }
}

// ---------------- launch ----------------

extern "C" void kernel_launch(void* const* d_in, const int* in_sizes, int n_in,
                              void* d_out, int out_size, void* d_ws, size_t ws_size,
                              hipStream_t stream) {
    const float* x   = (const float*)d_in[0];
    const int*   ei  = (const int*)d_in[1];
    const float* W1l = (const float*)d_in[2];
    const float* b1  = (const float*)d_in[3];
    const float* W1r = (const float*)d_in[4];
    const float* W2l = (const float*)d_in[5];
    const float* b2  = (const float*)d_in[6];
    const float* W2r = (const float*)d_in[7];
    const float* W3  = (const float*)d_in[8];
    const float* b3  = (const float*)d_in[9];
    float* out = (float*)d_out;

    const int N = in_sizes[0] / FDIM;   // 50000
    const int E = in_sizes[1] / 2;      // 800000
    const int* src = ei;
    const int* dst = ei + E;
    const int NBK = (N + 255) >> 8;     // 196

    char* ws = (char*)d_ws;
    size_t p = 0;
    auto alloc = [&](size_t bytes) {
        char* q = ws + p;
        p += (bytes + 255) & ~(size_t)255;
        return q;
    };
    int* ctrl    = (int*)alloc(272 * 4);          // bcnt[256] + hdone
    int* bcnt    = ctrl;
    int* hdone   = ctrl + 256;
    int* bbase   = (int*)alloc(260 * 4);
    int* bcur    = (int*)alloc(256 * 4);
    uint* pairs  = (uint*)alloc((size_t)E * 4);
    int* csr     = (int*)alloc((size_t)E * 4);
    int* off     = (int*)alloc((size_t)(N + 1) * 4);
    ushort* xbn  = (ushort*)alloc((size_t)N * FDIM * 2);
    uchar*  xf8  = (uchar*)alloc((size_t)N * FDIM);
    ushort* h1n  = (ushort*)alloc((size_t)N * FDIM * 2);
    uchar*  h1f8 = (uchar*)alloc((size_t)N * FDIM);
    ushort* wbuf = (ushort*)alloc(73728 * 2);
    ushort* w1l = wbuf, *w1r = wbuf + 16384, *w2l = wbuf + 32768,
           *w2r = wbuf + 49152, *w3 = wbuf + 65536;

    hipMemsetAsync(ctrl, 0, 257 * 4, stream);

    const int nx8   = N * FDIM / 8;         // 800000
    const int nconv = (nx8 + 255) / 256;    // 3125
    const int nhist = (E + 2047) / 2048;    // 391
    prep_kernel<<<nconv + 36 + nhist, 256, 0, stream>>>(
        x, xbn, xf8, nx8, W1l, W1r, W2l, W2r, W3, wbuf, dst, E, bcnt,
        hdone, bbase, bcur, NBK, nconv, nhist);
    pair_scatter<<<(E + 2047) / 2048, 256, 0, stream>>>(src, dst, bcur, pairs, E);
    bucket_csr<<<NBK, 256, 0, stream>>>(pairs, bbase, off, csr, N);

    const int lgrid = (N + 15) / 16;    // 3125
    fused_sage<0><<<lgrid, 256, 0, stream>>>(xf8, xbn, off, csr, w1l, w1r, b1,
                                             (const ushort*)nullptr, (const float*)nullptr,
                                             h1n, h1f8, (float*)nullptr, N);
    fused_sage<1><<<lgrid, 256, 0, stream>>>(h1f8, h1n, off, csr, w2l, w2r, b2,
                                             w3, b3, (ushort*)nullptr, (uchar*)nullptr, out, N);
}

// Round 12
// 163.777 us; speedup vs baseline: 1.8487x; 1.0139x over previous
//
#include <hip/hip_runtime.h>

#define FDIM 128

typedef __attribute__((ext_vector_type(8))) short bf16x8;
typedef __attribute__((ext_vector_type(4))) float f32x4;
typedef __attribute__((ext_vector_type(2))) float f32x2;

static __device__ __forceinline__ ushort f2bf(float f) {
    uint u = __float_as_uint(f);
    uint r = (u + 0x7FFF + ((u >> 16) & 1)) >> 16;
    return (ushort)r;
}
static __device__ __forceinline__ uint packbf(float lo, float hi) {
    return (uint)f2bf(lo) | ((uint)f2bf(hi) << 16);
}
static __device__ __forceinline__ uint pk8(float a, float b, float c, float d) {
    uint u = __builtin_amdgcn_cvt_pk_fp8_f32(a, b, 0, false);
    return __builtin_amdgcn_cvt_pk_fp8_f32(c, d, u, true);
}
static __device__ __forceinline__ uchar pk1(float v) {
    return (uchar)(__builtin_amdgcn_cvt_pk_fp8_f32(v, v, 0, false) & 0xFF);
}

// unpack 8 fp8 (uint2) and accumulate into a[0..7]
#define ACCF8(A, V) do { \
    f32x2 p0 = __builtin_amdgcn_cvt_pk_f32_fp8((V).x, false); \
    f32x2 p1 = __builtin_amdgcn_cvt_pk_f32_fp8((V).x, true);  \
    f32x2 p2 = __builtin_amdgcn_cvt_pk_f32_fp8((V).y, false); \
    f32x2 p3 = __builtin_amdgcn_cvt_pk_f32_fp8((V).y, true);  \
    A[0] += p0.x; A[1] += p0.y; A[2] += p1.x; A[3] += p1.y;   \
    A[4] += p2.x; A[5] += p2.y; A[6] += p3.x; A[7] += p3.y; } while (0)

// ---------------- prep: x -> bf16 + fp8 tables, weights bf16, histogram+scan ----------------

__global__ void prep_kernel(const float* __restrict__ x, ushort* __restrict__ xbn,
                            uchar* __restrict__ xf8, int nx8,
                            const float* __restrict__ W1l, const float* __restrict__ W1r,
                            const float* __restrict__ W2l, const float* __restrict__ W2r,
                            const float* __restrict__ W3, ushort* __restrict__ wbuf,
                            const int* __restrict__ dst, int E, int* __restrict__ bcnt,
                            int* __restrict__ hdone, int* __restrict__ bbase,
                            int* __restrict__ bcur, int nb, int nconv, int nhist) {
    const int b = blockIdx.x;
    const int tid = threadIdx.x;
    if (b < nconv) {
        int i = b * 256 + tid;
        if (i < nx8) {
            const float* s = x + (size_t)i * 8;
            float4 a = *(const float4*)(s);
            float4 c = *(const float4*)(s + 4);
            uint4 o;
            o.x = packbf(a.x, a.y); o.y = packbf(a.z, a.w);
            o.z = packbf(c.x, c.y); o.w = packbf(c.z, c.w);
            *(uint4*)(xbn + (size_t)i * 8) = o;
            uint2 q;
            q.x = pk8(a.x, a.y, a.z, a.w);
            q.y = pk8(c.x, c.y, c.z, c.w);
            *(uint2*)(xf8 + (size_t)i * 8) = q;
        }
    } else if (b < nconv + 36) {
        int c = (b - nconv) * 256 + tid;      // 0..9215 chunks of 8
        const float* s; ushort* d;
        if (c < 2048)      { s = W1l + (size_t)c * 8;          d = wbuf + (size_t)c * 8; }
        else if (c < 4096) { s = W1r + (size_t)(c - 2048) * 8; d = wbuf + 16384 + (size_t)(c - 2048) * 8; }
        else if (c < 6144) { s = W2l + (size_t)(c - 4096) * 8; d = wbuf + 32768 + (size_t)(c - 4096) * 8; }
        else if (c < 8192) { s = W2r + (size_t)(c - 6144) * 8; d = wbuf + 49152 + (size_t)(c - 6144) * 8; }
        else               { s = W3  + (size_t)(c - 8192) * 8; d = wbuf + 65536 + (size_t)(c - 8192) * 8; }
        float4 a = *(const float4*)(s);
        float4 cc = *(const float4*)(s + 4);
        uint4 o;
        o.x = packbf(a.x, a.y); o.y = packbf(a.z, a.w);
        o.z = packbf(cc.x, cc.y); o.w = packbf(cc.z, cc.w);
        *(uint4*)d = o;
    } else {
        __shared__ int lh[256];
        __shared__ int isLast;
        int hb = b - nconv - 36;
        lh[tid] = 0;
        __syncthreads();
        #pragma unroll
        for (int k = 0; k < 8; ++k) {
            int e = hb * 2048 + k * 256 + tid;
            if (e < E) atomicAdd(&lh[dst[e] >> 8], 1);
        }
        __syncthreads();
        if (lh[tid]) atomicAdd(&bcnt[tid], lh[tid]);
        __syncthreads();
        if (tid == 0) {
            __threadfence();
            isLast = (atomicAdd(hdone, 1) == nhist - 1);
        }
        __syncthreads();
        if (isLast && tid < 64) {
            __threadfence();
            volatile int* vb = bcnt;
            const int i0 = tid * 4;
            int v0 = (i0 + 0 < nb) ? vb[i0 + 0] : 0;
            int v1 = (i0 + 1 < nb) ? vb[i0 + 1] : 0;
            int v2 = (i0 + 2 < nb) ? vb[i0 + 2] : 0;
            int v3 = (i0 + 3 < nb) ? vb[i0 + 3] : 0;
            int s = v0 + v1 + v2 + v3;
            int incl = s;
            #pragma unroll
            for (int d = 1; d < 64; d <<= 1) {
                int t = __shfl_up(incl, d);
                if (tid >= d) incl += t;
            }
            int excl = incl - s;
            int e0 = excl, e1 = excl + v0, e2 = e1 + v1, e3 = e2 + v2;
            if (i0 + 0 < nb) { bbase[i0 + 0] = e0; bcur[i0 + 0] = e0; }
            if (i0 + 1 < nb) { bbase[i0 + 1] = e1; bcur[i0 + 1] = e1; }
            if (i0 + 2 < nb) { bbase[i0 + 2] = e2; bcur[i0 + 2] = e2; }
            if (i0 + 3 < nb) { bbase[i0 + 3] = e3; bcur[i0 + 3] = e3; }
            int total = __shfl(incl, 63);
            if (tid == 0) bbase[nb] = total;
        }
    }
}

// ---------------- bin edges into bucket-contiguous packed (src | dlow<<24) ----------------

__global__ void pair_scatter(const int* __restrict__ src, const int* __restrict__ dst,
                             int* __restrict__ bcur, uint* __restrict__ pairs, int E) {
    __shared__ int lh[256];
    __shared__ int gb[256];
    const int tid = threadIdx.x;
    lh[tid] = 0;
    __syncthreads();
    int ss[8], dd[8], sl[8];
    #pragma unroll
    for (int k = 0; k < 8; ++k) {
        int e = blockIdx.x * 2048 + k * 256 + tid;
        if (e < E) {
            ss[k] = src[e];
            dd[k] = dst[e];
            sl[k] = atomicAdd(&lh[dd[k] >> 8], 1);
        } else dd[k] = -1;
    }
    __syncthreads();
    if (lh[tid]) gb[tid] = atomicAdd(&bcur[tid], lh[tid]);
    __syncthreads();
    #pragma unroll
    for (int k = 0; k < 8; ++k) {
        if (dd[k] >= 0)
            pairs[gb[dd[k] >> 8] + sl[k]] = (uint)ss[k] | ((uint)(dd[k] & 255) << 24);
    }
}

// ---------------- per-bucket CSR: LDS count/scan/scatter ----------------

__global__ void bucket_csr(const uint* __restrict__ pairs, const int* __restrict__ bbase,
                           int* __restrict__ off, int* __restrict__ csr, int N) {
    __shared__ int cnt[256];
    __shared__ int base[256];
    __shared__ int cur[256];
    const int b = blockIdx.x;
    const int tid = threadIdx.x;
    const int p0 = bbase[b], p1 = bbase[b + 1];
    cnt[tid] = 0;
    __syncthreads();
    for (int p = p0 + tid; p < p1; p += 256) atomicAdd(&cnt[pairs[p] >> 24], 1);
    __syncthreads();
    if (tid < 64) {
        int i0 = tid * 4;
        int v0 = cnt[i0], v1 = cnt[i0 + 1], v2 = cnt[i0 + 2], v3 = cnt[i0 + 3];
        int s = v0 + v1 + v2 + v3;
        int incl = s;
        #pragma unroll
        for (int d = 1; d < 64; d <<= 1) {
            int t = __shfl_up(incl, d);
            if (tid >= d) incl += t;
        }
        int excl = incl - s;
        base[i0] = excl; base[i0 + 1] = excl + v0;
        base[i0 + 2] = excl + v0 + v1; base[i0 + 3] = excl + v0 + v1 + v2;
        cur[i0] = base[i0]; cur[i0 + 1] = base[i0 + 1];
        cur[i0 + 2] = base[i0 + 2]; cur[i0 + 3] = base[i0 + 3];
    }
    __syncthreads();
    int node = (b << 8) + tid;
    if (node <= N) off[node] = p0 + base[tid];
    for (int p = p0 + tid; p < p1; p += 256) {
        uint e = pairs[p];
        int slot = atomicAdd(&cur[e >> 24], 1);
        csr[p0 + slot] = (int)(e & 0xFFFFFF);
    }
}

// ---------------- fused SAGE layer: node-parallel k-loop fp8 gather + MFMA ----------------
// block = 256 thr (4 waves), 16 nodes/block, grid = 3125.
// Gather: lane = (node_sub = lane>>4, chunk = lane&15). Per 16-neighbor batch:
// one coalesced csr load (16 idx / 64 B per node-group), then k-loop shfl-broadcasts
// indices and issues up to 16 independent feat wave-loads. No cross-lane reduce:
// each lane owns chunk c of its node end-to-end and writes its own uint4.
// MFMA: operand-split waves, psum merge. HEAD=0: h -> bf16 + fp8 tables.
// HEAD=1: h kept in LDS, W3 head -> fp32 out.

#define PS 132

template<int HEAD>
__global__ __launch_bounds__(256, 8)
void fused_sage(const uchar* __restrict__ feat8, const ushort* __restrict__ featn,
                const int* __restrict__ off, const int* __restrict__ csr,
                const ushort* __restrict__ Wl, const ushort* __restrict__ Wr,
                const float* __restrict__ bias,
                const ushort* __restrict__ W3, const float* __restrict__ b3,
                ushort* __restrict__ houtn, uchar* __restrict__ hout8,
                float* __restrict__ fout, int n) {
    __shared__ __align__(16) ushort As[16 * FDIM];
    __shared__ __align__(16) ushort Xs[16 * FDIM];
    __shared__ __align__(16) float psum[16 * PS];
    const int row0 = blockIdx.x * 16;
    const int lane = threadIdx.x & 63;
    const int wid  = threadIdx.x >> 6;

    // stage self rows (bf16): 16 rows x 16 chunks = 256 threads, one 16B load each
    {
        int r = threadIdx.x >> 4, cch = threadIdx.x & 15;
        int row = row0 + r;
        float4 vx = make_float4(0.f, 0.f, 0.f, 0.f);
        if (row < n) vx = *(const float4*)(featn + (size_t)row * FDIM + cch * 8);
        *(float4*)(Xs + (r * 16 + (cch ^ (r & 7))) * 8) = vx;
    }

    // gather-mean from fp8 table: 4 nodes per wave, node-parallel k-loop
    {
        const int nsub = lane >> 4;   // node within wave 0..3
        const int c    = lane & 15;   // 8B chunk 0..15 of 128B row
        const int nodebase = row0 + wid * 4;
        int offv = off[min(nodebase + min(lane, 4), n)];
        const int j0  = __shfl(offv, nsub);
        const int j1  = __shfl(offv, nsub + 1);
        const int deg = j1 - j0;
        int md = max(deg, __shfl_xor(deg, 16));
        md = max(md, __shfl_xor(md, 32));

        float a[8] = {0.f, 0.f, 0.f, 0.f, 0.f, 0.f, 0.f, 0.f};
        for (int base = 0; base < md; base += 16) {
            int idx = (base + c < deg) ? csr[j0 + base + c] : 0;
            #pragma unroll
            for (int k = 0; k < 16; ++k) {
                int s = __shfl(idx, (nsub << 4) | k);
                if (base + k < deg) {
                    uint2 v = *(const uint2*)(feat8 + (size_t)s * FDIM + c * 8);
                    ACCF8(a, v);
                }
            }
        }
        float inv = 1.0f / fmaxf((float)deg, 1.0f);
        const int r = wid * 4 + nsub;
        uint4 o;
        o.x = packbf(a[0] * inv, a[1] * inv);
        o.y = packbf(a[2] * inv, a[3] * inv);
        o.z = packbf(a[4] * inv, a[5] * inv);
        o.w = packbf(a[6] * inv, a[7] * inv);
        *(uint4*)(As + (r * 16 + (c ^ (r & 7))) * 8) = o;
    }
    __syncthreads();

    // MFMA: wave role (op, half)
    const int op   = wid >> 1;          // 0: As@Wl, 1: Xs@Wr
    const int half = wid & 1;           // column half (64 cols)
    const int lr = lane & 15;
    const int lk = lane >> 4;
    const ushort* Atile = op ? Xs : As;
    const ushort* W     = op ? Wr : Wl;

    f32x4 acc[4];
    #pragma unroll
    for (int t = 0; t < 4; ++t) acc[t] = (f32x4){0.f, 0.f, 0.f, 0.f};

    #pragma unroll
    for (int ks = 0; ks < 4; ++ks) {
        bf16x8 a = *(const bf16x8*)(Atile + (lr * 16 + ((ks * 4 + lk) ^ (lr & 7))) * 8);
        #pragma unroll
        for (int t = 0; t < 4; ++t) {
            int wr = half * 64 + t * 16 + lr;
            bf16x8 bb = *(const bf16x8*)(W + (size_t)wr * FDIM + ks * 32 + lk * 8);
            acc[t] = __builtin_amdgcn_mfma_f32_16x16x32_bf16(a, bb, acc[t], 0, 0, 0);
        }
    }

    if (op == 1) {
        #pragma unroll
        for (int t = 0; t < 4; ++t) {
            #pragma unroll
            for (int j = 0; j < 4; ++j)
                psum[(lk * 4 + j) * PS + half * 64 + t * 16 + lr] = acc[t][j];
        }
    }
    __syncthreads();

    if (op == 0) {
        #pragma unroll
        for (int t = 0; t < 4; ++t) {
            int col = half * 64 + t * 16 + lr;
            float bc = bias[col];
            #pragma unroll
            for (int j = 0; j < 4; ++j) {
                int r = lk * 4 + j;
                float v = fmaxf(acc[t][j] + psum[r * PS + col] + bc, 0.f);
                if (HEAD == 0) {
                    int row = row0 + r;
                    if (row < n) {
                        houtn[(size_t)row * FDIM + col] = f2bf(v);
                        hout8[(size_t)row * FDIM + col] = pk1(v);
                    }
                } else {
                    As[(r * 16 + ((col >> 3) ^ (r & 7))) * 8 + (col & 7)] = f2bf(v);
                }
            }
        }
    }

    if (HEAD == 1) {
        __syncthreads();
        // head: out = h2 @ W3^T + b3; each wave: 16 out cols (wid*16)
        f32x4 acc2 = (f32x4){0.f, 0.f, 0.f, 0.f};
        #pragma unroll
        for (int ks = 0; ks < 4; ++ks) {
            bf16x8 a = *(const bf16x8*)(As + (lr * 16 + ((ks * 4 + lk) ^ (lr & 7))) * 8);
            int wr = wid * 16 + lr;
            bf16x8 bb = *(const bf16x8*)(W3 + (size_t)wr * FDIM + ks * 32 + lk * 8);
            acc2 = __builtin_amdgcn_mfma_f32_16x16x32_bf16(a, bb, acc2, 0, 0, 0);
        }
        int col = wid * 16 + lr;
        float bc = b3[col];
        #pragma unroll
        for (int j = 0; j < 4; ++j) {
            int row = row0 + lk * 4 + j;
            if (row < n) fout[(size_t)row * 64 + col] = acc2[j] + bc;
        }
    }
}

// ---------------- launch ----------------

extern "C" void kernel_launch(void* const* d_in, const int* in_sizes, int n_in,
                              void* d_out, int out_size, void* d_ws, size_t ws_size,
                              hipStream_t stream) {
    const float* x   = (const float*)d_in[0];
    const int*   ei  = (const int*)d_in[1];
    const float* W1l = (const float*)d_in[2];
    const float* b1  = (const float*)d_in[3];
    const float* W1r = (const float*)d_in[4];
    const float* W2l = (const float*)d_in[5];
    const float* b2  = (const float*)d_in[6];
    const float* W2r = (const float*)d_in[7];
    const float* W3  = (const float*)d_in[8];
    const float* b3  = (const float*)d_in[9];
    float* out = (float*)d_out;

    const int N = in_sizes[0] / FDIM;   // 50000
    const int E = in_sizes[1] / 2;      // 800000
    const int* src = ei;
    const int* dst = ei + E;
    const int NBK = (N + 255) >> 8;     // 196

    char* ws = (char*)d_ws;
    size_t p = 0;
    auto alloc = [&](size_t bytes) {
        char* q = ws + p;
        p += (bytes + 255) & ~(size_t)255;
        return q;
    };
    int* ctrl    = (int*)alloc(272 * 4);          // bcnt[256] + hdone
    int* bcnt    = ctrl;
    int* hdone   = ctrl + 256;
    int* bbase   = (int*)alloc(260 * 4);
    int* bcur    = (int*)alloc(256 * 4);
    uint* pairs  = (uint*)alloc((size_t)E * 4);
    int* csr     = (int*)alloc((size_t)E * 4);
    int* off     = (int*)alloc((size_t)(N + 1) * 4);
    ushort* xbn  = (ushort*)alloc((size_t)N * FDIM * 2);
    uchar*  xf8  = (uchar*)alloc((size_t)N * FDIM);
    ushort* h1n  = (ushort*)alloc((size_t)N * FDIM * 2);
    uchar*  h1f8 = (uchar*)alloc((size_t)N * FDIM);
    ushort* wbuf = (ushort*)alloc(73728 * 2);
    ushort* w1l = wbuf, *w1r = wbuf + 16384, *w2l = wbuf + 32768,
           *w2r = wbuf + 49152, *w3 = wbuf + 65536;

    hipMemsetAsync(ctrl, 0, 257 * 4, stream);

    const int nx8   = N * FDIM / 8;         // 800000
    const int nconv = (nx8 + 255) / 256;    // 3125
    const int nhist = (E + 2047) / 2048;    // 391
    prep_kernel<<<nconv + 36 + nhist, 256, 0, stream>>>(
        x, xbn, xf8, nx8, W1l, W1r, W2l, W2r, W3, wbuf, dst, E, bcnt,
        hdone, bbase, bcur, NBK, nconv, nhist);
    pair_scatter<<<(E + 2047) / 2048, 256, 0, stream>>>(src, dst, bcur, pairs, E);
    bucket_csr<<<NBK, 256, 0, stream>>>(pairs, bbase, off, csr, N);

    const int lgrid = (N + 15) / 16;    // 3125
    fused_sage<0><<<lgrid, 256, 0, stream>>>(xf8, xbn, off, csr, w1l, w1r, b1,
                                             (const ushort*)nullptr, (const float*)nullptr,
                                             h1n, h1f8, (float*)nullptr, N);
    fused_sage<1><<<lgrid, 256, 0, stream>>>(h1f8, h1n, off, csr, w2l, w2r, b2,
                                             w3, b3, (ushort*)nullptr, (uchar*)nullptr, out, N);
}